// Round 3
// baseline (172.284 us; speedup 1.0000x reference)
//
#include <hip/hip_runtime.h>
#include <hip/hip_bf16.h>
#include <string.h>

// SSIM3D on (8,1,32,256,256) f32, separable Gaussian window (5,11,11).
// y/x convs run on matrix cores (bf16 MFMA band-GEMMs); z-conv + SSIM on VALU (f32).

typedef __attribute__((ext_vector_type(4))) float  f32x4;
typedef __attribute__((ext_vector_type(8))) short  s16x8;
typedef __attribute__((ext_vector_type(4))) short  s16x4;

#define N_BATCH 8
#define DEPTH   32
#define HEIGHT  256
#define WIDTH   256
#define HW      (HEIGHT*WIDTH)
#define COUNT   16777216.0
#define NACC    64

// ---- LDS arena layout (bytes) ----
// B1 (GEMM1 B-operand, z-convolved fields, frag order): ks0 1KB + ks1 0.5KB per (f,nt)
#define B1KS0(f,nt) ((((f)*3+(nt))) << 10)                 // 15 * 1024 = 15360
#define B1KS1(f,nt) (15360 + ((((f)*3+(nt))) << 9))        // 15 * 512  =  7680
// A2 (GEMM2 A-operand, y-convolved, frag order): per (f,mt)
#define A2KS0(f,mt) (23040 + ((((f)*2+(mt))) << 10))       // 10 * 1024 = 10240
#define A2KS1(f,mt) (33280 + ((((f)*2+(mt))) << 9))        // 10 * 512  =  5120
#define TAB_OFF  38400
#define WRED_OFF 38432
#define LDS_BYTES 38448

// bf16(wy) for sigma=1.5,n=11, zero-padded at both ends (index = d+1, d in [-1..11])
static __device__ const unsigned short WYB[13] = {
  0, 0x3A87, 0x3BF9, 0x3D13, 0x3DE0, 0x3E5A, 0x3E88,
     0x3E5A, 0x3DE0, 0x3D13, 0x3BF9, 0x3A87, 0};

__global__ __launch_bounds__(256, 4) void ssim3d_mfma(
    const float* __restrict__ img1, const float* __restrict__ img2,
    double* __restrict__ acc)
{
  __shared__ __align__(16) unsigned char LDSA[LDS_BYTES];
  const int tid = threadIdx.x;

  // z-weights (f32), pre-multiplied by 1/(sum(bf16(wy))*sum(bf16(wx))) = 1.00161906
  const float WZ[5] = {0.00963569f, 0.20575600f, 0.57083462f, 0.20575600f, 0.00963569f};

  // ---- block decode + XCD swizzle (one batch n per XCD)
  int bid = blockIdx.x;
  bid = (bid & 7) * 2048 + (bid >> 3);
  const int txi = bid & 7, tyi = (bid >> 3) & 7, z_out = (bid >> 6) & 31, n = bid >> 11;
  const int y0 = tyi * 32 - 5, x0 = txi * 32 - 5;

  const int l = tid & 63, q = l >> 4, p = l & 15, w = tid >> 6;

  // ---- weight table to LDS; zero pad cols (nt=2, L&15 in 10..15)
  if (tid < 13) ((unsigned short*)(LDSA + TAB_OFF))[tid] = WYB[tid];
  if (tid < 120) {
    int f = tid / 24, s = tid % 24;
    int L = (s / 6) * 16 + 10 + (s % 6);
    *(uint4*)(LDSA + B1KS0(f,2) + L*16) = make_uint4(0,0,0,0);
    *(uint2*)(LDSA + B1KS1(f,2) + L*8)  = make_uint2(0,0);
  }

  // ---- stage 1: z-conv of 5 fields into registers (col-strip mapping)
  // thread (tid<252): col-pair cp = tid%21 (x = 2cp,2cp+1), row group g = tid/21 (rows 4g..4g+3)
  float zacc[5][4][2] = {};
  const int cp = tid % 21, g = tid / 21;
  if (tid < 252) {
    const int gx0 = x0 + 2*cp;
    const size_t nbase = (size_t)n * DEPTH * HW;
    int rowoff[4]; float mrow[4];
#pragma unroll
    for (int i = 0; i < 4; ++i) {
      int yh = 4*g + i, gy = y0 + yh;
      int gyc = min(max(gy, 0), 255);
      rowoff[i] = gyc * WIDTH;
      mrow[i] = (yh < 42 && (unsigned)gy < 256u) ? 1.f : 0.f;
    }
    if (txi >= 1 && txi <= 6) {  // x fully interior (uniform branch)
#pragma unroll
      for (int kz = 0; kz < 5; ++kz) {
        int z_in = z_out + kz - 2;
        if ((unsigned)z_in >= 32u) continue;
        const float wzv = WZ[kz];
        const float* p1 = img1 + nbase + (size_t)z_in * HW;
        const float* p2 = img2 + nbase + (size_t)z_in * HW;
#pragma unroll
        for (int i = 0; i < 4; ++i) {
          float2 va, vb;
          memcpy(&va, p1 + rowoff[i] + gx0, 8);
          memcpy(&vb, p2 + rowoff[i] + gx0, 8);
          float u0 = wzv*va.x, v0 = wzv*vb.x;
          zacc[0][i][0] += u0; zacc[1][i][0] += v0;
          zacc[2][i][0] = fmaf(u0, va.x, zacc[2][i][0]);
          zacc[3][i][0] = fmaf(v0, vb.x, zacc[3][i][0]);
          zacc[4][i][0] = fmaf(u0, vb.x, zacc[4][i][0]);
          float u1 = wzv*va.y, v1 = wzv*vb.y;
          zacc[0][i][1] += u1; zacc[1][i][1] += v1;
          zacc[2][i][1] = fmaf(u1, va.y, zacc[2][i][1]);
          zacc[3][i][1] = fmaf(v1, vb.y, zacc[3][i][1]);
          zacc[4][i][1] = fmaf(u1, vb.y, zacc[4][i][1]);
        }
      }
#pragma unroll
      for (int f = 0; f < 5; ++f)
#pragma unroll
      for (int i = 0; i < 4; ++i) { zacc[f][i][0] *= mrow[i]; zacc[f][i][1] *= mrow[i]; }
    } else {  // x-edge tiles: scalar loads, per-column clamp+mask
      int xo0 = min(max(gx0, 0), 255), xo1 = min(max(gx0+1, 0), 255);
      float mc0 = ((unsigned)gx0 < 256u) ? 1.f : 0.f;
      float mc1 = ((unsigned)(gx0+1) < 256u) ? 1.f : 0.f;
#pragma unroll
      for (int kz = 0; kz < 5; ++kz) {
        int z_in = z_out + kz - 2;
        if ((unsigned)z_in >= 32u) continue;
        const float wzv = WZ[kz];
        const float* p1 = img1 + nbase + (size_t)z_in * HW;
        const float* p2 = img2 + nbase + (size_t)z_in * HW;
#pragma unroll
        for (int i = 0; i < 4; ++i) {
          float a0 = p1[rowoff[i] + xo0], a1_ = p1[rowoff[i] + xo1];
          float b0 = p2[rowoff[i] + xo0], b1_ = p2[rowoff[i] + xo1];
          float u0 = wzv*a0, v0 = wzv*b0;
          zacc[0][i][0] += u0; zacc[1][i][0] += v0;
          zacc[2][i][0] = fmaf(u0, a0, zacc[2][i][0]);
          zacc[3][i][0] = fmaf(v0, b0, zacc[3][i][0]);
          zacc[4][i][0] = fmaf(u0, b0, zacc[4][i][0]);
          float u1 = wzv*a1_, v1 = wzv*b1_;
          zacc[0][i][1] += u1; zacc[1][i][1] += v1;
          zacc[2][i][1] = fmaf(u1, a1_, zacc[2][i][1]);
          zacc[3][i][1] = fmaf(v1, b1_, zacc[3][i][1]);
          zacc[4][i][1] = fmaf(u1, b1_, zacc[4][i][1]);
        }
      }
#pragma unroll
      for (int f = 0; f < 5; ++f)
#pragma unroll
      for (int i = 0; i < 4; ++i) {
        zacc[f][i][0] *= mrow[i]*mc0; zacc[f][i][1] *= mrow[i]*mc1;
      }
    }

    // ---- stage 2: zacc -> B1 in MFMA B-fragment order (packed bf16 b64 writes)
    // value at (k=yh=4g+i, n=2cp+c): ks=k>>5, L=(n&15)+16*(g&3), ks0 byte 8*(g>>2)+2i, ks1 byte 2i
#pragma unroll
    for (int f = 0; f < 5; ++f) {
#pragma unroll
      for (int c = 0; c < 2; ++c) {
        int nn = 2*cp + c, nt = nn >> 4, nL = nn & 15;
        __hip_bfloat162 h01 = __float22bfloat162_rn(make_float2(zacc[f][0][c], zacc[f][1][c]));
        __hip_bfloat162 h23 = __float22bfloat162_rn(make_float2(zacc[f][2][c], zacc[f][3][c]));
        uint2 val; memcpy(&val.x, &h01, 4); memcpy(&val.y, &h23, 4);
        int off;
        if (g < 8) off = B1KS0(f,nt) + (nL + 16*(g&3))*16 + 8*(g>>2);
        else       off = B1KS1(f,nt) + (nL + 16*(g&3))*8;
        *(uint2*)(LDSA + off) = val;
      }
    }
  }
  __syncthreads();  // TAB + B1 (+pads) ready

  // ---- constant band fragments (A1 = Wy 32x42 band; B2 = WxT 42x32 band)
  const unsigned short* TAB = (const unsigned short*)(LDSA + TAB_OFF);
  s16x8 a1[2][2], b2[2];
  const int nt2 = w & 1, mt2 = w >> 1;
#pragma unroll
  for (int mt = 0; mt < 2; ++mt)
#pragma unroll
  for (int ks = 0; ks < 2; ++ks) {
    s16x8 r;
#pragma unroll
    for (int j = 0; j < 8; ++j) {
      int k = 32*ks + 4*q + (j&3) + 16*(j>>2);
      int d = min(max(k - 16*mt - p + 1, 0), 12);
      r[j] = (ks == 1 && j >= 4) ? (short)0 : (short)TAB[d];
    }
    a1[mt][ks] = r;
  }
#pragma unroll
  for (int ks = 0; ks < 2; ++ks) {
    s16x8 r;
#pragma unroll
    for (int j = 0; j < 8; ++j) {
      int k = 32*ks + 4*q + (j&3) + 16*(j>>2);
      int d = min(max(k - 16*nt2 - p + 1, 0), 12);
      r[j] = (ks == 1 && j >= 4) ? (short)0 : (short)TAB[d];
    }
    b2[ks] = r;
  }

  // ---- GEMM1: O1 = Wy * F ; write D to A2 in A-fragment order (bf16)
#pragma unroll
  for (int uu = 0; uu < 4; ++uu) {
    int u = w + 4*uu;
    if (u < 15) {
      int f = (u * 11) >> 5, nt = u - 3*f;
      s16x8 bk0 = *(const s16x8*)(LDSA + B1KS0(f,nt) + l*16);
      s16x4 blo = *(const s16x4*)(LDSA + B1KS1(f,nt) + l*8);
      s16x8 bk1 = {blo[0], blo[1], blo[2], blo[3], 0, 0, 0, 0};
      f32x4 acc0 = {0,0,0,0}, acc1 = {0,0,0,0};
      acc0 = __builtin_amdgcn_mfma_f32_16x16x32_bf16(a1[0][0], bk0, acc0, 0, 0, 0);
      acc0 = __builtin_amdgcn_mfma_f32_16x16x32_bf16(a1[0][1], bk1, acc0, 0, 0, 0);
      acc1 = __builtin_amdgcn_mfma_f32_16x16x32_bf16(a1[1][0], bk0, acc1, 0, 0, 0);
      acc1 = __builtin_amdgcn_mfma_f32_16x16x32_bf16(a1[1][1], bk1, acc1, 0, 0, 0);
      // D elem r: y = 16mt + 4q + r, x = 16nt + p  ->  A2 (m=y, k=x)
#pragma unroll
      for (int mt = 0; mt < 2; ++mt) {
        f32x4 av = mt ? acc1 : acc0;
#pragma unroll
        for (int r = 0; r < 4; ++r) {
          __hip_bfloat16 hb = __float2bfloat16(av[r]);
          unsigned short hv; memcpy(&hv, &hb, 2);
          int off;
          if (nt < 2) off = A2KS0(f,mt) + ((4*q + r) + 16*(p>>2))*16 + ((p&3) + 4*nt)*2;
          else        off = A2KS1(f,mt) + ((4*q + r) + 16*(p>>2))*8  + (p&3)*2;
          *(unsigned short*)(LDSA + off) = hv;
        }
      }
    }
  }
  __syncthreads();

  // ---- GEMM2: O2 = O1 * WxT ; wave w owns output tile (mt2, nt2); then SSIM
  float lsum = 0.f;
  {
    f32x4 o[5];
#pragma unroll
    for (int f = 0; f < 5; ++f) {
      s16x8 ak0 = *(const s16x8*)(LDSA + A2KS0(f,mt2) + l*16);
      s16x4 alo = *(const s16x4*)(LDSA + A2KS1(f,mt2) + l*8);
      s16x8 ak1 = {alo[0], alo[1], alo[2], alo[3], 0, 0, 0, 0};
      f32x4 t = {0,0,0,0};
      t = __builtin_amdgcn_mfma_f32_16x16x32_bf16(ak0, b2[0], t, 0, 0, 0);
      t = __builtin_amdgcn_mfma_f32_16x16x32_bf16(ak1, b2[1], t, 0, 0, 0);
      o[f] = t;
    }
    const float C1 = 0.0001f, C2 = 0.0009f;
#pragma unroll
    for (int r = 0; r < 4; ++r) {
      float mu1 = o[0][r], mu2 = o[1][r];
      float m11 = mu1*mu1, m22 = mu2*mu2, m12 = mu1*mu2;
      float s1 = o[2][r] - m11, s2 = o[3][r] - m22, s12 = o[4][r] - m12;
      float num = (2.f*m12 + C1) * (2.f*s12 + C2);
      float den = (m11 + m22 + C1) * (s1 + s2 + C2);
      lsum += num / den;
    }
  }

  // ---- reduction
#pragma unroll
  for (int off_ = 32; off_ > 0; off_ >>= 1) lsum += __shfl_down(lsum, off_, 64);
  if ((tid & 63) == 0) ((float*)(LDSA + WRED_OFF))[w] = lsum;
  __syncthreads();
  if (tid == 0) {
    float* wr = (float*)(LDSA + WRED_OFF);
    atomicAdd(&acc[blockIdx.x & (NACC - 1)], (double)(wr[0] + wr[1] + wr[2] + wr[3]));
  }
}

__global__ void ssim3d_finalize(const double* __restrict__ acc, float* __restrict__ out)
{
  double s = 0.0;
  for (int i = 0; i < NACC; ++i) s += acc[i];
  out[0] = 1.0f - (float)(s / COUNT);
}

extern "C" void kernel_launch(void* const* d_in, const int* in_sizes, int n_in,
                              void* d_out, int out_size, void* d_ws, size_t ws_size,
                              hipStream_t stream)
{
  const float* img1 = (const float*)d_in[0];
  const float* img2 = (const float*)d_in[1];
  float* out = (float*)d_out;
  double* acc = (double*)d_ws;

  hipMemsetAsync(d_ws, 0, NACC * sizeof(double), stream);

  const int n_blocks = N_BATCH * DEPTH * 8 * 8;  // 16384
  ssim3d_mfma<<<dim3(n_blocks), dim3(256), 0, stream>>>(img1, img2, acc);
  ssim3d_finalize<<<1, 1, 0, stream>>>(acc, out);
}

// Round 4
// 163.576 us; speedup vs baseline: 1.0532x; 1.0532x over previous
//
#include <hip/hip_runtime.h>
#include <math.h>

// SSIM3D on (8,1,32,256,256) f32, separable Gaussian (5,11,11).
// All-f32 VALU pipeline with packed-fp32 (v_pk_fma_f32) pairing:
//  - stage1 z-conv: column-pair f32x2, aligned dwordx2 global loads
//  - y-conv: column-pair f32x2 over LDS planes
//  - x-conv: row-pair f32x2 via ds_read2-mergeable LDS reads
//  - SSIM: packed math + v_rcp_f32

typedef __attribute__((ext_vector_type(2))) float f32x2;

#define DEPTH   32
#define HEIGHT  256
#define WIDTH   256
#define HW      (HEIGHT*WIDTH)
#define COUNT   16777216.0
#define NACC    64

// halo: 44 cols (x0 = 32*txi - 6, even-aligned), rows 0..41 used (y0 = 32*tyi - 5);
// plane rows 42,43 are scratch so stage-1 writes need no row masking.
#define PSTR 44
#define PROWS 44

struct Weights { float wz[5]; float wy[11]; };

__device__ __forceinline__ f32x2 fma2(f32x2 a, f32x2 b, f32x2 c) {
#if __has_builtin(__builtin_elementwise_fma)
  return __builtin_elementwise_fma(a, b, c);
#else
  f32x2 r; r.x = fmaf(a.x, b.x, c.x); r.y = fmaf(a.y, b.y, c.y); return r;
#endif
}
__device__ __forceinline__ f32x2 bc2(float v) { f32x2 r; r.x = v; r.y = v; return r; }

__global__ __launch_bounds__(256, 4) void ssim3d_pk(
    const float* __restrict__ img1, const float* __restrict__ img2,
    double* __restrict__ acc, Weights W)
{
  __shared__ __align__(16) float P[5][PROWS * PSTR];   // 5 * 7744 B = 38720 B
  __shared__ float wred[4];
  const int tid = threadIdx.x;

  // XCD swizzle: one batch n per XCD (16384 blocks, 8 XCDs)
  int bid = blockIdx.x;
  bid = (bid & 7) * 2048 + (bid >> 3);
  const int txi = bid & 7, tyi = (bid >> 3) & 7, z_out = (bid >> 6) & 31, n = bid >> 11;
  const int x0 = txi * 32 - 6;   // even halo origin
  const int y0 = tyi * 32 - 5;

  // ---- stage 1: z-conv of 5 fields, column-pair packed
  // thread -> (cp = tid%22: cols 2cp,2cp+1; g = tid/22: rows 4g..4g+3); 242 active
  const int cp = tid % 22, g = tid / 22;
  f32x2 zacc[4][5];
#pragma unroll
  for (int i = 0; i < 4; ++i)
#pragma unroll
    for (int f = 0; f < 5; ++f) zacc[i][f] = bc2(0.f);

  if (g < 11) {
    const size_t nbase = (size_t)n * DEPTH * HW;
    const int gx0 = x0 + 2 * cp;
    int rofs[4]; float mr[4];
#pragma unroll
    for (int i = 0; i < 4; ++i) {
      int gy = y0 + 4 * g + i;
      int gyc = min(max(gy, 0), 255);
      rofs[i] = gyc * WIDTH;
      mr[i] = ((unsigned)gy < 256u) ? 1.f : 0.f;
    }

    if (gx0 >= 0 && gx0 <= 254) {   // aligned pair fully in-bounds
#pragma unroll
      for (int kz = 0; kz < 5; ++kz) {
        int z_in = z_out + kz - 2;
        if ((unsigned)z_in >= 32u) continue;   // zero pad in z
        const f32x2 wz2 = bc2(W.wz[kz]);
        const float* p1 = img1 + nbase + (size_t)z_in * HW + gx0;
        const float* p2 = img2 + nbase + (size_t)z_in * HW + gx0;
#pragma unroll
        for (int i = 0; i < 4; ++i) {
          f32x2 A = *(const f32x2*)(p1 + rofs[i]);
          f32x2 B = *(const f32x2*)(p2 + rofs[i]);
          f32x2 t = wz2 * A, u = wz2 * B;
          zacc[i][0] += t;
          zacc[i][1] += u;
          zacc[i][2] = fma2(t, A, zacc[i][2]);
          zacc[i][3] = fma2(u, B, zacc[i][3]);
          zacc[i][4] = fma2(t, B, zacc[i][4]);
        }
      }
#pragma unroll
      for (int i = 0; i < 4; ++i) {
        f32x2 m = bc2(mr[i]);
#pragma unroll
        for (int f = 0; f < 5; ++f) zacc[i][f] *= m;
      }
    } else {   // x-edge threads: clamped scalar loads + column masks
      const int xo0 = min(max(gx0, 0), 255), xo1 = min(max(gx0 + 1, 0), 255);
      const float mx0 = ((unsigned)gx0 < 256u) ? 1.f : 0.f;
      const float mx1 = ((unsigned)(gx0 + 1) < 256u) ? 1.f : 0.f;
#pragma unroll
      for (int kz = 0; kz < 5; ++kz) {
        int z_in = z_out + kz - 2;
        if ((unsigned)z_in >= 32u) continue;
        const f32x2 wz2 = bc2(W.wz[kz]);
        const float* p1 = img1 + nbase + (size_t)z_in * HW;
        const float* p2 = img2 + nbase + (size_t)z_in * HW;
#pragma unroll
        for (int i = 0; i < 4; ++i) {
          f32x2 A, B;
          A.x = p1[rofs[i] + xo0]; A.y = p1[rofs[i] + xo1];
          B.x = p2[rofs[i] + xo0]; B.y = p2[rofs[i] + xo1];
          f32x2 t = wz2 * A, u = wz2 * B;
          zacc[i][0] += t;
          zacc[i][1] += u;
          zacc[i][2] = fma2(t, A, zacc[i][2]);
          zacc[i][3] = fma2(u, B, zacc[i][3]);
          zacc[i][4] = fma2(t, B, zacc[i][4]);
        }
      }
#pragma unroll
      for (int i = 0; i < 4; ++i) {
        f32x2 m; m.x = mr[i] * mx0; m.y = mr[i] * mx1;
#pragma unroll
        for (int f = 0; f < 5; ++f) zacc[i][f] *= m;
      }
    }

    // ---- stage 2: packed b64 writes to planes (rows 42,43 = scratch, no mask)
#pragma unroll
    for (int i = 0; i < 4; ++i) {
      int row = 4 * g + i;
#pragma unroll
      for (int f = 0; f < 5; ++f)
        *(f32x2*)&P[f][row * PSTR + 2 * cp] = zacc[i][f];
    }
  }
  __syncthreads();

  // ---- stage 3: y-conv, column-pair packed; 3 rows/thread, 242 active
  const int g2 = tid / 22, xp = tid % 22;
  f32x2 yout[3][5];
  if (tid < 242) {
#pragma unroll
    for (int f = 0; f < 5; ++f) {
      f32x2 win[13];
#pragma unroll
      for (int i = 0; i < 13; ++i)
        win[i] = *(const f32x2*)&P[f][(3 * g2 + i) * PSTR + 2 * xp];
#pragma unroll
      for (int r = 0; r < 3; ++r) {
        f32x2 s = bc2(0.f);
#pragma unroll
        for (int j = 0; j < 11; ++j) s = fma2(bc2(W.wy[j]), win[r + j], s);
        yout[r][f] = s;
      }
    }
  }
  __syncthreads();
  if (tid < 242) {
#pragma unroll
    for (int r = 0; r < 3; ++r) {
      int y = 3 * g2 + r;
      if (y < 32) {
#pragma unroll
        for (int f = 0; f < 5; ++f)
          *(f32x2*)&P[f][y * PSTR + 2 * xp] = yout[r][f];
      }
    }
  }
  __syncthreads();

  // ---- stage 4: x-conv (row-pair packed) + SSIM (packed) over 4 values/thread
  const int rp = tid >> 4, xg = tid & 15;   // rows {2rp,2rp+1}, out cols {2xg,2xg+1}
  float lsum = 0.f;
  {
    f32x2 s[5][2];
#pragma unroll
    for (int f = 0; f < 5; ++f) {
      f32x2 w2[12];
      const float* r0 = &P[f][(2 * rp) * PSTR + 2 * xg + 1];
      const float* r1 = r0 + PSTR;
#pragma unroll
      for (int j = 0; j < 12; ++j) { f32x2 v; v.x = r0[j]; v.y = r1[j]; w2[j] = v; }
      f32x2 s0 = bc2(0.f), s1 = bc2(0.f);
#pragma unroll
      for (int j = 0; j < 11; ++j) {
        f32x2 wv = bc2(W.wy[j]);
        s0 = fma2(wv, w2[j],     s0);
        s1 = fma2(wv, w2[j + 1], s1);
      }
      s[f][0] = s0; s[f][1] = s1;
    }
    const f32x2 c1 = bc2(1e-4f), c2 = bc2(9e-4f), two = bc2(2.f);
#pragma unroll
    for (int k = 0; k < 2; ++k) {
      f32x2 mu1 = s[0][k], mu2 = s[1][k];
      f32x2 m11 = mu1 * mu1, m22 = mu2 * mu2, m12 = mu1 * mu2;
      f32x2 sg1 = s[2][k] - m11, sg2 = s[3][k] - m22, sg12 = s[4][k] - m12;
      f32x2 num = fma2(two, m12, c1) * fma2(two, sg12, c2);
      f32x2 den = (m11 + m22 + c1) * (sg1 + sg2 + c2);
#if __has_builtin(__builtin_amdgcn_rcpf)
      lsum += num.x * __builtin_amdgcn_rcpf(den.x)
            + num.y * __builtin_amdgcn_rcpf(den.y);
#else
      lsum += num.x / den.x + num.y / den.y;
#endif
    }
  }

  // ---- reduction
#pragma unroll
  for (int off = 32; off > 0; off >>= 1) lsum += __shfl_down(lsum, off, 64);
  if ((tid & 63) == 0) wred[tid >> 6] = lsum;
  __syncthreads();
  if (tid == 0) {
    float bs = wred[0] + wred[1] + wred[2] + wred[3];
    atomicAdd(&acc[blockIdx.x & (NACC - 1)], (double)bs);
  }
}

__global__ void ssim3d_finalize(const double* __restrict__ acc, float* __restrict__ out)
{
  double s = 0.0;
  for (int i = 0; i < NACC; ++i) s += acc[i];
  out[0] = 1.0f - (float)(s / COUNT);
}

static Weights make_weights()
{
  Weights W;
  double gbuf[11]; double s;

  s = 0.0;
  for (int i = 0; i < 5; ++i) {
    double d = i - 2;
    gbuf[i] = exp(-(d * d) / (2.0 * 0.7 * 0.7));
    s += gbuf[i];
  }
  for (int i = 0; i < 5; ++i) W.wz[i] = (float)(gbuf[i] / s);

  s = 0.0;
  for (int i = 0; i < 11; ++i) {
    double d = i - 5;
    gbuf[i] = exp(-(d * d) / (2.0 * 1.5 * 1.5));
    s += gbuf[i];
  }
  for (int i = 0; i < 11; ++i) W.wy[i] = (float)(gbuf[i] / s);

  return W;
}

extern "C" void kernel_launch(void* const* d_in, const int* in_sizes, int n_in,
                              void* d_out, int out_size, void* d_ws, size_t ws_size,
                              hipStream_t stream)
{
  const float* img1 = (const float*)d_in[0];
  const float* img2 = (const float*)d_in[1];
  float* out = (float*)d_out;
  double* acc = (double*)d_ws;

  hipMemsetAsync(d_ws, 0, NACC * sizeof(double), stream);

  Weights W = make_weights();

  const int n_blocks = 8 * DEPTH * 8 * 8;   // 16384
  ssim3d_pk<<<dim3(n_blocks), dim3(256), 0, stream>>>(img1, img2, acc, W);
  ssim3d_finalize<<<1, 1, 0, stream>>>(acc, out);
}